// Round 11
// baseline (492.515 us; speedup 1.0000x reference)
//
#include <hip/hip_runtime.h>
#include <cmath>

typedef unsigned short u16;
typedef unsigned int   u32;
typedef short bf16x8 __attribute__((ext_vector_type(8)));
typedef float f32x4 __attribute__((ext_vector_type(4)));

// Problem constants
constexpr int B_ = 8, T_ = 32, N_ = 24, D_ = 128;
constexpr int BT_ = B_ * T_;            // 256
constexpr int VW_ = N_ * N_;            // 576
constexpr int BTN_ = BT_ * N_;          // 6144
constexpr int BTVW_ = BT_ * VW_;        // 147456
constexpr int P_ = 3;
constexpr int C_ = 6;
constexpr int SA_ = 136;                // k_fused A row stride (u16); /2=68 u32
constexpr int SP_ = 130;                // k_prep ME-staging row stride (u16)

__device__ __forceinline__ float bits2f(u32 u) { float f; __builtin_memcpy(&f, &u, 4); return f; }
__device__ __forceinline__ float bf2f(u16 h) { return bits2f(((u32)h) << 16); }
__device__ __forceinline__ u16 f2bf(float f) {
    u32 u; __builtin_memcpy(&u, &f, 4);
    u32 r = u + 0x7FFFu + ((u >> 16) & 1u);
    return (u16)(r >> 16);
}
__device__ __forceinline__ float sigm(float x) { return 1.0f / (1.0f + expf(-x)); }

// ---------------------------------------------------------------------------
// Canonicalize all 17 weight/bias arrays (fp32 -> bf16) + build transposed
// LSTM Whh (WT[kk*1024 + j*2 + p] = Whh[j*128 + kk*2 + p]) in ONE launch.
// ---------------------------------------------------------------------------
struct CvtArgs {
    const void* src[17];
    u16* dst[17];
    int start[18];
    const float* whh;   // raw fp32 lstm_Whh (d_in[14])
    u16* wthh;          // transposed bf16 out
};

__global__ __launch_bounds__(256) void k_convall(CvtArgs a) {
    const int idx = blockIdx.x * 256 + threadIdx.x;
    const int total = a.start[17];
    if (idx < total) {
        int s = 0;
#pragma unroll
        for (int i = 1; i < 17; ++i) s += (idx >= a.start[i]) ? 1 : 0;
        const int off = idx - a.start[s];
        a.dst[s][off] = f2bf(((const float*)a.src[s])[off]);
    } else {
        const int off = idx - total;
        if (off < 65536) {
            const int kk = off >> 10, rem = off & 1023;
            const int j = rem >> 1, p = rem & 1;
            a.wthh[off] = f2bf(a.whh[j * 128 + kk * 2 + p]);
        }
    }
}

// ---------------------------------------------------------------------------
// Transpose node_resnet [bt, d, n] fp32 -> HN fp32 + HNb bf16 [bt, n, d].
// ---------------------------------------------------------------------------
__global__ __launch_bounds__(256) void k_transpose_node(const float* __restrict__ node,
                                                        float* __restrict__ HN,
                                                        u16* __restrict__ HNb) {
    const int bt = blockIdx.x;
    for (int f = threadIdx.x; f < 3072; f += 256) {
        const int d = f / 24, n = f - d * 24;
        const float v = node[(size_t)bt * 3072 + f];
        HN[(size_t)bt * 3072 + n * 128 + d] = v;
        HNb[(size_t)bt * 3072 + n * 128 + d] = f2bf(v);
    }
}

// ---------------------------------------------------------------------------
// k_prep: fused edge transpose + ME GEMM + layer-0 link-MLP.
// Per block: (bt, 64 vw rows). A-fragments loaded DIRECTLY from global into
// registers (32 independent scalar loads/thread; 64-B coalesced chunks per
// instruction; no staging LDS, no barrier before MFMA). ME written through a
// padded LDS buffer for fully-coalesced 16-B stores.
// ---------------------------------------------------------------------------
__global__ __launch_bounds__(256) void k_prep(
    const float* __restrict__ edge, const u16* __restrict__ We,
    const u16* __restrict__ W1, const u16* __restrict__ b1,
    const u16* __restrict__ W2, const u16* __restrict__ b2,
    u16* __restrict__ ME, float* __restrict__ ADJ) {
    __shared__ __align__(16) u16 S[64 * SP_];   // ME staging, padded
    const int tid = threadIdx.x;
    const int bt = blockIdx.x / 9, tile = blockIdx.x % 9;
    const int vw0 = tile * 64;
    const int wv = tid >> 6, lane = tid & 63;
    const int m = lane & 15, quad = lane >> 4;
    const int row = wv * 16 + m;                // 0..63 within tile
    const size_t ebase = (size_t)bt * D_ * VW_ + vw0 + row;

    // ---- direct global->register fragments (d-major gather) ----
    float fv[4][8];
#pragma unroll
    for (int ks = 0; ks < 4; ++ks)
#pragma unroll
        for (int j = 0; j < 8; ++j)
            fv[ks][j] = edge[ebase + (size_t)(ks * 32 + quad * 8 + j) * VW_];
    bf16x8 a[4];
#pragma unroll
    for (int ks = 0; ks < 4; ++ks) {
        u16 tmp[8];
#pragma unroll
        for (int j = 0; j < 8; ++j) tmp[j] = f2bf(fv[ks][j]);
        __builtin_memcpy(&a[ks], tmp, 16);
    }
    const f32x4 z = {0.f, 0.f, 0.f, 0.f};

    // ---- ME = A @ We^T, register-B halves; scatter results into LDS ----
#pragma unroll
    for (int h = 0; h < 2; ++h) {
        bf16x8 bw[4][4];
#pragma unroll
        for (int c4 = 0; c4 < 4; ++c4)
#pragma unroll
            for (int ks = 0; ks < 4; ++ks)
                bw[c4][ks] = *(const bf16x8*)&We[(size_t)((h * 4 + c4) * 16 + m) * 128 + ks * 32 + quad * 8];
        f32x4 acc[4];
#pragma unroll
        for (int c4 = 0; c4 < 4; ++c4) acc[c4] = z;
#pragma unroll
        for (int c4 = 0; c4 < 4; ++c4)
#pragma unroll
            for (int ks = 0; ks < 4; ++ks)
                acc[c4] = __builtin_amdgcn_mfma_f32_16x16x32_bf16(a[ks], bw[c4][ks], acc[c4], 0, 0, 0);
#pragma unroll
        for (int c4 = 0; c4 < 4; ++c4) {
            const int col = (h * 4 + c4) * 16 + m;
#pragma unroll
            for (int reg = 0; reg < 4; ++reg)
                S[(wv * 16 + quad * 4 + reg) * SP_ + col] = f2bf(acc[c4][reg]);
        }
    }

    // ---- layer-0 adjacency: relu(W1@A + b1) . W2 + b2 (register path) ----
    float p[4] = {0.f, 0.f, 0.f, 0.f};
    const float b2v = bf2f(b2[0]);
#pragma unroll
    for (int h = 0; h < 2; ++h) {
        bf16x8 bw[4][4];
#pragma unroll
        for (int c4 = 0; c4 < 4; ++c4)
#pragma unroll
            for (int ks = 0; ks < 4; ++ks)
                bw[c4][ks] = *(const bf16x8*)&W1[(size_t)((h * 4 + c4) * 16 + m) * 128 + ks * 32 + quad * 8];
        f32x4 acc[4];
#pragma unroll
        for (int c4 = 0; c4 < 4; ++c4) acc[c4] = z;
#pragma unroll
        for (int c4 = 0; c4 < 4; ++c4)
#pragma unroll
            for (int ks = 0; ks < 4; ++ks)
                acc[c4] = __builtin_amdgcn_mfma_f32_16x16x32_bf16(a[ks], bw[c4][ks], acc[c4], 0, 0, 0);
#pragma unroll
        for (int c4 = 0; c4 < 4; ++c4) {
            const int n = (h * 4 + c4) * 16 + m;
            const float b1v = bf2f(b1[n]);
            const float w2v = bf2f(W2[n]);
#pragma unroll
            for (int reg = 0; reg < 4; ++reg)
                p[reg] += fmaxf(acc[c4][reg] + b1v, 0.0f) * w2v;
        }
    }
#pragma unroll
    for (int reg = 0; reg < 4; ++reg) {
        p[reg] += __shfl_xor(p[reg], 1);
        p[reg] += __shfl_xor(p[reg], 2);
        p[reg] += __shfl_xor(p[reg], 4);
        p[reg] += __shfl_xor(p[reg], 8);
    }
    if (m == 0) {
#pragma unroll
        for (int reg = 0; reg < 4; ++reg)
            ADJ[bt * VW_ + vw0 + wv * 16 + quad * 4 + reg] = p[reg] + b2v;
    }

    // ---- coalesced ME store from LDS staging ----
    __syncthreads();
    const size_t mebase = (size_t)(bt * VW_ + vw0) * 128;
#pragma unroll
    for (int i = 0; i < 4; ++i) {
        const int chunk = tid + 256 * i;        // 0..1023
        const int r = chunk >> 4, k8 = chunk & 15;
        const bf16x8 v = *(const bf16x8*)&S[r * SP_ + k8 * 8];
        *(bf16x8*)&ME[mebase + (size_t)r * 128 + k8 * 8] = v;
    }
}

// ---------------------------------------------------------------------------
// Fused per-(bt, v-pair) edge kernel. 48 rows (2 v) per block, 256 threads.
// Build phase: batched unconditional loads, masked compute. ADJP: link-MLP
// via MFMA with register-preloaded W1 fragments (3 waves x 16 rows).
// ---------------------------------------------------------------------------
template <bool ADJP>
__global__ __launch_bounds__(256) void k_fused(
    const u16* __restrict__ ME, const float* __restrict__ XW,
    const u16* __restrict__ mb,
    const u16* __restrict__ W1, const u16* __restrict__ b1,
    const u16* __restrict__ W2, const u16* __restrict__ b2,
    const int* __restrict__ nnr, float* __restrict__ ADJ,
    u16* __restrict__ MVb) {
    __shared__ __align__(16) u16 A[48 * SA_];
    __shared__ float gate_s[48];
    __shared__ float2 mvp[2][2][64];
    const int tid = threadIdx.x;
    const int blk = blockIdx.x;
    const int bt = blk / 12, pr = blk - bt * 12;
    const int v0 = pr * 2;
    const int e0 = bt * VW_ + v0 * N_;
    const int nv = nnr[bt];

    if (tid < 48) gate_s[tid] = sigm(ADJ[e0 + tid]);
    __syncthreads();
    {
        const int op = tid & 63;            // o-pair: cols 2op, 2op+1
        const int sub = (tid >> 6) & 1;     // w-half
        const int grp = tid >> 7;           // v within pair
        const int v = v0 + grp;
        const u32 mbu = ((const u32*)mb)[op];
        const float mb0 = bf2f((u16)mbu), mb1 = bf2f((u16)(mbu >> 16));
        const bool vva = v < nv;
        u32 meR[12]; float2 xwR[12];
#pragma unroll
        for (int i = 0; i < 12; ++i) {
            const int w = sub * 12 + i;
            const int rr = grp * 24 + w;
            meR[i] = ((const u32*)ME)[(size_t)(e0 + rr) * 64 + op];
            xwR[i] = *(const float2*)&XW[(size_t)(bt * N_ + w) * 128 + 2 * op];
        }
        float mvx = 0.0f, mvy = 0.0f;
        u32* A32 = (u32*)A;
#pragma unroll
        for (int i = 0; i < 12; ++i) {
            const int w = sub * 12 + i;
            const int rr = grp * 24 + w;
            float v0f = 0.0f, v1f = 0.0f;
            if (vva && w < nv) {
                const float g = gate_s[rr];
                v0f = g * fmaxf(xwR[i].x + bf2f((u16)meR[i]) + mb0, 0.0f);
                v1f = g * fmaxf(xwR[i].y + bf2f((u16)(meR[i] >> 16)) + mb1, 0.0f);
                mvx += v0f; mvy += v1f;
            }
            if (ADJP) A32[rr * 68 + op] = (u32)f2bf(v0f) | ((u32)f2bf(v1f) << 16);
        }
        mvp[grp][sub][op] = make_float2(mvx, mvy);
    }
    __syncthreads();
    if (tid < 128) {
        const int g2 = tid >> 6, o2 = tid & 63;
        const float2 pa = mvp[g2][0][o2], pb = mvp[g2][1][o2];
        ((u32*)MVb)[(size_t)(bt * N_ + v0 + g2) * 64 + o2] =
            (u32)f2bf(pa.x + pb.x) | ((u32)f2bf(pa.y + pb.y) << 16);
    }

    if constexpr (ADJP) {
        __syncthreads();
        if (tid >= 192) return;
        const int wv = tid >> 6, lane = tid & 63;
        const int m = lane & 15, quad = lane >> 4;
        bf16x8 a[4];
#pragma unroll
        for (int ks = 0; ks < 4; ++ks)
            a[ks] = *(const bf16x8*)&A[(wv * 16 + m) * SA_ + ks * 32 + quad * 8];
        const f32x4 z = {0.f, 0.f, 0.f, 0.f};
        float p[4] = {0.f, 0.f, 0.f, 0.f};
        const float b2v = bf2f(b2[0]);
#pragma unroll
        for (int h = 0; h < 2; ++h) {
            bf16x8 bw[4][4];
#pragma unroll
            for (int c4 = 0; c4 < 4; ++c4)
#pragma unroll
                for (int ks = 0; ks < 4; ++ks)
                    bw[c4][ks] = *(const bf16x8*)&W1[(size_t)((h * 4 + c4) * 16 + m) * 128 + ks * 32 + quad * 8];
            f32x4 acc[4];
#pragma unroll
            for (int c4 = 0; c4 < 4; ++c4) acc[c4] = z;
#pragma unroll
            for (int c4 = 0; c4 < 4; ++c4)
#pragma unroll
                for (int ks = 0; ks < 4; ++ks)
                    acc[c4] = __builtin_amdgcn_mfma_f32_16x16x32_bf16(a[ks], bw[c4][ks], acc[c4], 0, 0, 0);
#pragma unroll
            for (int c4 = 0; c4 < 4; ++c4) {
                const int n = (h * 4 + c4) * 16 + m;
                const float b1v = bf2f(b1[n]);
                const float w2v = bf2f(W2[n]);
#pragma unroll
                for (int reg = 0; reg < 4; ++reg)
                    p[reg] += fmaxf(acc[c4][reg] + b1v, 0.0f) * w2v;
            }
        }
#pragma unroll
        for (int reg = 0; reg < 4; ++reg) {
            p[reg] += __shfl_xor(p[reg], 1);
            p[reg] += __shfl_xor(p[reg], 2);
            p[reg] += __shfl_xor(p[reg], 4);
            p[reg] += __shfl_xor(p[reg], 8);
        }
        if (m == 0) {
#pragma unroll
            for (int reg = 0; reg < 4; ++reg)
                ADJ[e0 + wv * 16 + quad * 4 + reg] = p[reg] + b2v;
        }
    }
}

// ---------------------------------------------------------------------------
// XW = HNb @ msg_Wh^T via MFMA. 192 blocks x 128 threads (2 waves x 16 rows).
// ---------------------------------------------------------------------------
__global__ __launch_bounds__(128) void k_xw(const u16* __restrict__ HNb,
                                            const u16* __restrict__ W,
                                            float* __restrict__ XW) {
    const int tid = threadIdx.x;
    const int wv = tid >> 6, lane = tid & 63;
    const int m = lane & 15, quad = lane >> 4;
    const int r0 = blockIdx.x * 32 + wv * 16;
    bf16x8 a[4];
#pragma unroll
    for (int ks = 0; ks < 4; ++ks)
        a[ks] = *(const bf16x8*)&HNb[(size_t)(r0 + m) * 128 + ks * 32 + quad * 8];
    const f32x4 z = {0.f, 0.f, 0.f, 0.f};
#pragma unroll
    for (int ct = 0; ct < 8; ++ct) {
        f32x4 acc = z;
        const int n = ct * 16 + m;
#pragma unroll
        for (int ks = 0; ks < 4; ++ks) {
            const bf16x8 b = *(const bf16x8*)&W[n * 128 + ks * 32 + quad * 8];
            acc = __builtin_amdgcn_mfma_f32_16x16x32_bf16(a[ks], b, acc, 0, 0, 0);
        }
#pragma unroll
        for (int reg = 0; reg < 4; ++reg)
            XW[(size_t)(r0 + quad * 4 + reg) * 128 + ct * 16 + m] = acc[reg];
    }
}

// ---------------------------------------------------------------------------
// Fused MFMA GRU: 32 rows/block (2 waves x 16), 128 threads, 192 blocks.
// ---------------------------------------------------------------------------
__global__ __launch_bounds__(128) void k_gruM(
    const u16* __restrict__ MVb, const u16* __restrict__ HNb_in,
    float* __restrict__ HN, u16* __restrict__ HNb,
    const u16* __restrict__ Wih, const u16* __restrict__ Whh,
    const u16* __restrict__ bih, const u16* __restrict__ bhh,
    const int* __restrict__ nnr) {
    __shared__ float bi_s[384], bh_s[384];
    const int tid = threadIdx.x;
    for (int f = tid; f < 384; f += 128) {
        bi_s[f] = bf2f(bih[f]);
        bh_s[f] = bf2f(bhh[f]);
    }
    const int wv = tid >> 6, lane = tid & 63;
    const int m = lane & 15, quad = lane >> 4;
    const int rbase = blockIdx.x * 32 + wv * 16;
    bf16x8 amv[4], ahn[4];
#pragma unroll
    for (int ks = 0; ks < 4; ++ks) {
        amv[ks] = *(const bf16x8*)&MVb[(size_t)(rbase + m) * 128 + ks * 32 + quad * 8];
        ahn[ks] = *(const bf16x8*)&HNb_in[(size_t)(rbase + m) * 128 + ks * 32 + quad * 8];
    }
    int rowg[4]; bool valid[4];
#pragma unroll
    for (int reg = 0; reg < 4; ++reg) {
        const int row = rbase + quad * 4 + reg;
        rowg[reg] = row;
        const int bt = row / N_, vv = row - bt * N_;
        valid[reg] = vv < nnr[bt];
    }
    __syncthreads();
    const f32x4 z = {0.f, 0.f, 0.f, 0.f};
#pragma unroll
    for (int ct = 0; ct < 8; ++ct) {
        f32x4 gi[3], gh[3];
#pragma unroll
        for (int g = 0; g < 3; ++g) { gi[g] = z; gh[g] = z; }
        const int col = ct * 16 + m;
#pragma unroll
        for (int g = 0; g < 3; ++g) {
            const size_t wrow = (size_t)(g * 128 + col) * 128;
#pragma unroll
            for (int ks = 0; ks < 4; ++ks) {
                const bf16x8 bi_f = *(const bf16x8*)&Wih[wrow + ks * 32 + quad * 8];
                const bf16x8 bh_f = *(const bf16x8*)&Whh[wrow + ks * 32 + quad * 8];
                gi[g] = __builtin_amdgcn_mfma_f32_16x16x32_bf16(amv[ks], bi_f, gi[g], 0, 0, 0);
                gh[g] = __builtin_amdgcn_mfma_f32_16x16x32_bf16(ahn[ks], bh_f, gh[g], 0, 0, 0);
            }
        }
        const float biR = bi_s[col], bhR = bh_s[col];
        const float biZ = bi_s[128 + col], bhZ = bh_s[128 + col];
        const float biN = bi_s[256 + col], bhN = bh_s[256 + col];
#pragma unroll
        for (int reg = 0; reg < 4; ++reg) {
            const float r = sigm(gi[0][reg] + gh[0][reg] + biR + bhR);
            const float zz = sigm(gi[1][reg] + gh[1][reg] + biZ + bhZ);
            const float nn = tanhf(gi[2][reg] + biN + r * (gh[2][reg] + bhN));
            const size_t oi = (size_t)rowg[reg] * 128 + col;
            const float h = HN[oi];
            const float hv = valid[reg] ? ((1.0f - zz) * nn + zz * h) : 0.0f;
            HN[oi] = hv;
            HNb[oi] = f2bf(hv);
        }
    }
}

// ---------------------------------------------------------------------------
// GI = HNb @ lstm_Wih^T + (bih+bhh). grid (192, 2) x 128 threads.
// ---------------------------------------------------------------------------
__global__ __launch_bounds__(128) void k_gi(const u16* __restrict__ HNb,
                                            const u16* __restrict__ W,
                                            const u16* __restrict__ bih, const u16* __restrict__ bhh,
                                            float* __restrict__ GI) {
    const int tid = threadIdx.x;
    const int wv = tid >> 6, lane = tid & 63;
    const int m = lane & 15, quad = lane >> 4;
    const int r0 = blockIdx.x * 32 + wv * 16;
    const int ocol0 = blockIdx.y * 256;
    bf16x8 a[4];
#pragma unroll
    for (int ks = 0; ks < 4; ++ks)
        a[ks] = *(const bf16x8*)&HNb[(size_t)(r0 + m) * 128 + ks * 32 + quad * 8];
    const f32x4 z = {0.f, 0.f, 0.f, 0.f};
#pragma unroll
    for (int ct = 0; ct < 16; ++ct) {
        f32x4 acc = z;
        const int col = ocol0 + ct * 16 + m;
#pragma unroll
        for (int ks = 0; ks < 4; ++ks) {
            const bf16x8 b = *(const bf16x8*)&W[(size_t)col * 128 + ks * 32 + quad * 8];
            acc = __builtin_amdgcn_mfma_f32_16x16x32_bf16(a[ks], b, acc, 0, 0, 0);
        }
        const float bsum = bf2f(bih[col]) + bf2f(bhh[col]);
#pragma unroll
        for (int reg = 0; reg < 4; ++reg)
            GI[(size_t)(r0 + quad * 4 + reg) * 512 + col] = acc[reg] + bsum;
    }
}

// ---------------------------------------------------------------------------
// Recurrent LSTM, Whh in registers. 192 blocks x 512 threads.
// ---------------------------------------------------------------------------
__global__ __launch_bounds__(512) void k_rec(const float* __restrict__ GI,
                                             const u16* __restrict__ WThh,
                                             float* __restrict__ OUTH) {
    __shared__ __align__(16) float h_s[128];
    __shared__ __align__(16) float g_s[512];
    const int tid = threadIdx.x;
    const int row = blockIdx.x;          // b*24+n
    const int bb = row / N_, nn = row - bb * N_;
    const u32* WT32 = (const u32*)WThh;
    u32 wt[64];
#pragma unroll
    for (int kk = 0; kk < 64; ++kk) wt[kk] = WT32[kk * 512 + tid];
    float c = 0.0f;
    if (tid < 128) h_s[tid] = 0.0f;
    __syncthreads();
    const size_t gb = (size_t)(bb * T_ * N_ + nn) * 512;
    float g = GI[gb + tid];
    for (int t = 0; t < T_; ++t) {
        float gnext = 0.0f;
        if (t + 1 < T_) gnext = GI[gb + (size_t)(t + 1) * (N_ * 512) + tid];
        float acc[4] = {0.f, 0.f, 0.f, 0.f};
#pragma unroll
        for (int k4 = 0; k4 < 32; ++k4) {
            const float4 h4 = *(const float4*)&h_s[k4 * 4];
            const u32 wA = wt[2 * k4], wB = wt[2 * k4 + 1];
            acc[k4 & 3] = fmaf(bits2f(wA << 16), h4.x,
                          fmaf(bits2f(wA & 0xFFFF0000u), h4.y,
                          fmaf(bits2f(wB << 16), h4.z,
                          fmaf(bits2f(wB & 0xFFFF0000u), h4.w, acc[k4 & 3]))));
        }
        g_s[tid] = g + (acc[0] + acc[1]) + (acc[2] + acc[3]);
        __syncthreads();
        if (tid < 128) {
            const float gi = g_s[tid], gf = g_s[128 + tid];
            const float gg = g_s[256 + tid], go = g_s[384 + tid];
            c = sigm(gf) * c + sigm(gi) * tanhf(gg);
            const float hv = sigm(go) * tanhf(c);
            h_s[tid] = hv;
            OUTH[((size_t)t * 192 + row) * 128 + tid] = hv;
        }
        __syncthreads();
        g = gnext;
    }
}

// ---------------------------------------------------------------------------
// Readout: out[b,t,n,c] = mask ? OUTH_row . ro_W[c] + ro_b[c] : 0   (fp32 out)
// ---------------------------------------------------------------------------
__global__ __launch_bounds__(256) void k_readout(const float* __restrict__ OUTH,
                                                 const u16* __restrict__ roW,
                                                 const u16* __restrict__ rob,
                                                 const int* __restrict__ nnr,
                                                 float* __restrict__ out) {
    const int idx = blockIdx.x * 256 + threadIdx.x;
    const int btn = idx / C_, c = idx - btn * C_;
    const int bt = btn / N_, n = btn - bt * N_;
    const int b = bt / T_, t = bt - b * T_;
    const int nv = nnr[bt];
    float val = 0.0f;
    if (n < nv) {
        const float* hrow = OUTH + ((size_t)t * 192 + b * N_ + n) * 128;
        float acc = bf2f(rob[c]);
        for (int k = 0; k < 128; ++k) acc += bf2f(roW[c * 128 + k]) * hrow[k];
        val = acc;
    }
    out[idx] = val;
}

// ---------------------------------------------------------------------------
extern "C" void kernel_launch(void* const* d_in, const int* in_sizes, int n_in,
                              void* d_out, int out_size, void* d_ws, size_t ws_size,
                              hipStream_t stream) {
    const float* node = (const float*)d_in[0];
    const float* edge = (const float*)d_in[1];
    const int* nnr = (const int*)d_in[19];

    // Workspace layout (~62 MB)
    char* ws = (char*)d_ws;
    float* HN = (float*)ws;   ws += (size_t)BTN_ * D_ * 4;    // 3.15 MB
    u16* HNb = (u16*)ws;      ws += (size_t)BTN_ * D_ * 2;    // 1.57 MB
    float* XW = (float*)ws;   ws += (size_t)BTN_ * D_ * 4;    // 3.15 MB
    u16* MVb = (u16*)ws;      ws += (size_t)BTN_ * D_ * 2;    // 1.57 MB
    float* ADJ = (float*)ws;  ws += (size_t)BTVW_ * 4;        // 0.59 MB
    float* GI = (float*)ws;   ws += (size_t)BTN_ * 512 * 4;   // 12.58 MB
    u16* WThh = (u16*)ws;     ws += 65536 * 2;                // 0.13 MB
    u16* ME = (u16*)ws;       ws += (size_t)BTVW_ * D_ * 2;   // 37.75 MB
    float* OUTH = XW;         // XW dead after last k_fused; same size

    // Canonical bf16 weights
    u16* cbase = (u16*)ws;
    const int cvtN[17] = {16384, 128, 128, 1, 16384, 16384, 128,
                          49152, 49152, 384, 384, 65536, 65536, 512, 512, 768, 6};
    CvtArgs ca;
    u16* cptr[17];
    {
        int off = 0;
        for (int i = 0; i < 17; ++i) {
            cptr[i] = cbase + off;
            ca.src[i] = d_in[2 + i];
            ca.dst[i] = cptr[i];
            off += (cvtN[i] + 7) & ~7;
        }
        int cum = 0;
        for (int i = 0; i < 17; ++i) { ca.start[i] = cum; cum += cvtN[i]; }
        ca.start[17] = cum;             // 281479
        ca.whh = (const float*)d_in[14];   // lstm_Whh
        ca.wthh = WThh;
    }
    u16* cW1 = cptr[0];  u16* cb1 = cptr[1];  u16* cW2 = cptr[2];  u16* cb2 = cptr[3];
    u16* cWh = cptr[4];  u16* cWe = cptr[5];  u16* cmb = cptr[6];
    u16* cgWih = cptr[7]; u16* cgWhh = cptr[8]; u16* cgbih = cptr[9]; u16* cgbhh = cptr[10];
    u16* clsWih = cptr[11]; u16* clsbih = cptr[13]; u16* clsbhh = cptr[14];
    u16* croW = cptr[15]; u16* crob = cptr[16];

    k_convall<<<(281479 + 65536 + 255) / 256, 256, 0, stream>>>(ca);
    k_transpose_node<<<BT_, 256, 0, stream>>>(node, HN, HNb);
    // fused: edge gather + ME GEMM + layer-0 adjacency (direct-reg fragments)
    k_prep<<<BT_ * 9, 256, 0, stream>>>(edge, cWe, cW1, cb1, cW2, cb2, ME, ADJ);
    for (int l = 0; l < P_; ++l) {
        k_xw<<<192, 128, 0, stream>>>(HNb, cWh, XW);
        if (l < P_ - 1)
            k_fused<true><<<BTN_ / 2, 256, 0, stream>>>(ME, XW, cmb, cW1, cb1, cW2, cb2,
                                                        nnr, ADJ, MVb);
        else
            k_fused<false><<<BTN_ / 2, 256, 0, stream>>>(ME, XW, cmb, cW1, cb1, cW2, cb2,
                                                         nnr, ADJ, MVb);
        k_gruM<<<192, 128, 0, stream>>>(MVb, HNb, HN, HNb, cgWih, cgWhh, cgbih, cgbhh, nnr);
    }
    k_gi<<<dim3(192, 2), 128, 0, stream>>>(HNb, clsWih, clsbih, clsbhh, GI);
    k_rec<<<192, 512, 0, stream>>>(GI, WThh, OUTH);
    k_readout<<<144, 256, 0, stream>>>(OUTH, croW, crob, nnr, (float*)d_out);
}